// Round 4
// baseline (405.489 us; speedup 1.0000x reference)
//
#include <hip/hip_runtime.h>

// LIF scan, two-pass decoupled: K1 computes chunk-boundary carries serially
// (one thread per chain, no output stores); K2 replays each 100-step chunk in
// parallel (10x the waves) with the identical op sequence and writes outputs.
// Bit-exact vs reference: v' = v + (i - v)/10.0f (IEEE div), spike = v' >= 1,
// reset via exact select (s in {0,1} makes v*(1-s)+0*s == select).

constexpr int B  = 32;
constexpr int T  = 1000;
constexpr int N  = 1024;
constexpr int BN = B * N;          // 32768 chains
constexpr int C  = 10;             // time chunks
constexpr int TC = T / C;          // 100 steps per chunk

// ---------------- K1: sequential boundary pass ----------------
constexpr int U1  = 20;
constexpr int NB1 = T / U1;        // 50 (even)

__global__ __launch_bounds__(64) void lif_boundary(
    const float* __restrict__ in,   // [B,T,N]
    const float* __restrict__ v0,   // [B,N]
    float* __restrict__ bnd)        // [C-1][BN]: v after step (k+1)*TC
{
    const int idx = blockIdx.x * 64 + threadIdx.x;
    const int b = idx >> 10;                 // N == 1024
    const int n = idx & (N - 1);
    const float* ip = in + (size_t)b * T * N + n;

    float v = v0[idx];
    float bufA[U1], bufB[U1];
    #pragma unroll
    for (int j = 0; j < U1; ++j) bufA[j] = ip[(size_t)j * N];

    for (int blk = 0; blk < NB1; blk += 2) {
        const int tA = blk * U1, tB = tA + U1, tN = tA + 2 * U1;

        #pragma unroll
        for (int j = 0; j < U1; ++j) bufB[j] = ip[(size_t)(tB + j) * N];
        #pragma unroll
        for (int j = 0; j < U1; ++j) {
            float nv = v + (bufA[j] - v) / 10.0f;
            v = (nv >= 1.0f) ? 0.0f : nv;
        }
        if ((tA + U1) % TC == 0 && (tA + U1) < T)
            bnd[(size_t)((tA + U1) / TC - 1) * BN + idx] = v;

        if (tN < T) {
            #pragma unroll
            for (int j = 0; j < U1; ++j) bufA[j] = ip[(size_t)(tN + j) * N];
        }
        #pragma unroll
        for (int j = 0; j < U1; ++j) {
            float nv = v + (bufB[j] - v) / 10.0f;
            v = (nv >= 1.0f) ? 0.0f : nv;
        }
        if ((tB + U1) % TC == 0 && (tB + U1) < T)
            bnd[(size_t)((tB + U1) / TC - 1) * BN + idx] = v;
    }
}

// ---------------- K2: parallel chunk replay ----------------
constexpr int U2 = 20;             // TC / U2 == 5 blocks per chunk

__device__ __forceinline__ void chunk_steps(const float (&buf)[U2], float& v,
                                            float* __restrict__ sp,
                                            float* __restrict__ vp, int t0)
{
    float sb[U2], vb[U2];
    #pragma unroll
    for (int j = 0; j < U2; ++j) {
        float nv = v + (buf[j] - v) / 10.0f;
        const bool fire = (nv >= 1.0f);
        sb[j] = fire ? 1.0f : 0.0f;
        nv = fire ? 0.0f : nv;
        vb[j] = nv;
        v = nv;
    }
    #pragma unroll
    for (int j = 0; j < U2; ++j) {
        sp[(size_t)(t0 + j) * N] = sb[j];
        vp[(size_t)(t0 + j) * N] = vb[j];
    }
}

__global__ __launch_bounds__(256) void lif_chunks(
    const float* __restrict__ in,   // [B,T,N]
    const float* __restrict__ v0,   // [BN]
    const float* __restrict__ bnd,  // [C-1][BN]
    float* __restrict__ spk,
    float* __restrict__ vol)
{
    const int g   = blockIdx.x * 256 + threadIdx.x;   // 0 .. C*BN-1
    const int idx = g & (BN - 1);
    const int c   = g >> 15;                          // BN == 2^15 (uniform/block)
    const int b   = idx >> 10;
    const int n   = idx & (N - 1);
    const size_t base = (size_t)b * T * N + (size_t)c * TC * N + n;
    const float* ip = in  + base;
    float*       sp = spk + base;
    float*       vp = vol + base;

    float v = (c == 0) ? v0[idx] : bnd[(size_t)(c - 1) * BN + idx];

    float bufA[U2], bufB[U2];
    #pragma unroll
    for (int j = 0; j < U2; ++j) bufA[j] = ip[(size_t)j * N];
    #pragma unroll
    for (int j = 0; j < U2; ++j) bufB[j] = ip[(size_t)(U2 + j) * N];
    chunk_steps(bufA, v, sp, vp, 0);
    #pragma unroll
    for (int j = 0; j < U2; ++j) bufA[j] = ip[(size_t)(2 * U2 + j) * N];
    chunk_steps(bufB, v, sp, vp, U2);
    #pragma unroll
    for (int j = 0; j < U2; ++j) bufB[j] = ip[(size_t)(3 * U2 + j) * N];
    chunk_steps(bufA, v, sp, vp, 2 * U2);
    #pragma unroll
    for (int j = 0; j < U2; ++j) bufA[j] = ip[(size_t)(4 * U2 + j) * N];
    chunk_steps(bufB, v, sp, vp, 3 * U2);
    chunk_steps(bufA, v, sp, vp, 4 * U2);
}

// ---------------- fallback (round-2 single kernel) ----------------
__device__ __forceinline__ void fb_steps(const float (&buf)[U1], float& v,
                                         float* __restrict__ sp,
                                         float* __restrict__ vp, int t0)
{
    float sb[U1], vb[U1];
    #pragma unroll
    for (int j = 0; j < U1; ++j) {
        float nv = v + (buf[j] - v) / 10.0f;
        const bool fire = (nv >= 1.0f);
        sb[j] = fire ? 1.0f : 0.0f;
        nv = fire ? 0.0f : nv;
        vb[j] = nv;
        v = nv;
    }
    #pragma unroll
    for (int j = 0; j < U1; ++j) {
        sp[(size_t)(t0 + j) * N] = sb[j];
        vp[(size_t)(t0 + j) * N] = vb[j];
    }
}

__global__ __launch_bounds__(64) void lif_fused(
    const float* __restrict__ in, const float* __restrict__ v0,
    float* __restrict__ spk, float* __restrict__ vol)
{
    const int idx = blockIdx.x * 64 + threadIdx.x;
    const int b = idx >> 10;
    const int n = idx & (N - 1);
    const size_t base = (size_t)b * T * N + n;
    const float* ip = in + base;
    float* sp = spk + base;
    float* vp = vol + base;

    float v = v0[idx];
    float bufA[U1], bufB[U1];
    #pragma unroll
    for (int j = 0; j < U1; ++j) bufA[j] = ip[(size_t)j * N];

    for (int blk = 0; blk < NB1; blk += 2) {
        const int tA = blk * U1, tB = tA + U1, tN = tA + 2 * U1;
        #pragma unroll
        for (int j = 0; j < U1; ++j) bufB[j] = ip[(size_t)(tB + j) * N];
        fb_steps(bufA, v, sp, vp, tA);
        if (tN < T) {
            #pragma unroll
            for (int j = 0; j < U1; ++j) bufA[j] = ip[(size_t)(tN + j) * N];
        }
        fb_steps(bufB, v, sp, vp, tB);
    }
}

extern "C" void kernel_launch(void* const* d_in, const int* in_sizes, int n_in,
                              void* d_out, int out_size, void* d_ws, size_t ws_size,
                              hipStream_t stream) {
    const float* in = (const float*)d_in[0];   // [B,T,N]
    const float* v0 = (const float*)d_in[1];   // [B,N]
    float* spk = (float*)d_out;
    float* vol = (float*)d_out + (size_t)B * T * N;

    const size_t bnd_bytes = (size_t)(C - 1) * BN * sizeof(float);
    if (ws_size >= bnd_bytes) {
        float* bnd = (float*)d_ws;
        lif_boundary<<<BN / 64, 64, 0, stream>>>(in, v0, bnd);
        lif_chunks<<<(C * BN) / 256, 256, 0, stream>>>(in, v0, bnd, spk, vol);
    } else {
        lif_fused<<<BN / 64, 64, 0, stream>>>(in, v0, spk, vol);
    }
}